// Round 8
// baseline (265.274 us; speedup 1.0000x reference)
//
#include <hip/hip_runtime.h>
#include <cstdint>
#include <cstddef>

#define BATCH 32
#define NCLS 81
#define NFG 80
#define NBOX 15130
#define NCHUNK 60         // ceil(15130/256)
#define TOPK 200
#define NTASK (BATCH * NFG)
#define NEG_INF -1e30f
#define GCAP 1024         // per-task candidate capacity (measured mean ~434)
#define SORTCAP 1024
#define LCAP 4864         // 256 boxes * max 19 classes/box (hard bound: sum p = 1)
#define SCORE_THR 0.05f
#define CRITERIA 0.45f

// ---------------------------------------------------------------- K1: decode + softmax + compacted candidate emission
// ROUND-2 LESSON: vals[81] must be DEAD after the sum loop; the phase-3
// re-read goes through an asm-laundered pointer so the compiler cannot CSE
// it back to vals[] and extend liveness (spill -> 990 us).
// ROUND-3 LESSON: no per-element global atomics on few hot addresses
// (1900 us). Emission batches ONE global atomicAdd per (block,class).
// ROUND-4/5/6 LESSON: per-(b,c) blocks must not re-stream 60 KB each from
// the L2-miss path (~115 us floor); k2 reads ~3.5 KB compacted lists.
__global__ __launch_bounds__(256) void k1_fused(
    const float* __restrict__ bboxes,   // [B,4,N]
    const float* __restrict__ scores,   // [B,C,N]
    const float* __restrict__ dboxes,   // [N,4]
    float4* __restrict__ ltrb,          // [B*N]
    unsigned long long* __restrict__ gcand,  // [NTASK*GCAP]
    int* __restrict__ gcnt)             // [NTASK] (zeroed before launch)
{
    const int blk = blockIdx.x;
    const int b = blk / NCHUNK;
    const int chunk = blk - b * NCHUNK;
    const int tid = threadIdx.x;
    const int n = chunk * 256 + tid;

    __shared__ unsigned long long list[LCAP];   // (p_bits<<32)|(cfg<<24)|n
    __shared__ int lcnt;
    __shared__ int ccnt[NFG];
    __shared__ int cbase[NFG];

    if (tid == 0) lcnt = 0;
    if (tid < NFG) ccnt[tid] = 0;
    __syncthreads();

    float m = 0.f, s = 1.f, thrv = 1e30f;
    const float* sc = scores;           // set properly below when n valid

    if (n < NBOX) {
        // ---- decode (bit-exact, validated rounds 1-7)
        const float* bb = bboxes + (size_t)b * 4 * NBOX + n;
        float bx = bb[0];
        float by = bb[NBOX];
        float bw = bb[2 * (size_t)NBOX];
        float bh = bb[3 * (size_t)NBOX];
        float4 d = reinterpret_cast<const float4*>(dboxes)[n];  // cx, cy, w, h
        float xx = __fadd_rn(__fmul_rn(__fmul_rn(0.1f, bx), d.z), d.x);
        float yy = __fadd_rn(__fmul_rn(__fmul_rn(0.1f, by), d.w), d.y);
        float wx = __fmul_rn(expf(__fmul_rn(0.2f, bw)), d.z);
        float wy = __fmul_rn(expf(__fmul_rn(0.2f, bh)), d.w);
        float4 o;
        o.x = __fsub_rn(xx, __fmul_rn(0.5f, wx));
        o.y = __fsub_rn(yy, __fmul_rn(0.5f, wy));
        o.z = __fadd_rn(xx, __fmul_rn(0.5f, wx));
        o.w = __fadd_rn(yy, __fmul_rn(0.5f, wy));
        ltrb[(size_t)b * NBOX + n] = o;

        // ---- softmax stats (vals[] dead after this scope)
        sc = scores + (size_t)b * NCLS * NBOX + n;
        {
            float vals[NCLS];
#pragma unroll
            for (int c = 0; c < NCLS; ++c) vals[c] = sc[(size_t)c * NBOX];
            m = vals[0];
#pragma unroll
            for (int c = 1; c < NCLS; ++c) m = fmaxf(m, vals[c]);
            float ss = 0.0f;
#pragma unroll
            for (int c = 0; c < NCLS; ++c) ss = __fadd_rn(ss, expf(__fsub_rn(vals[c], m)));
            s = ss;
        }
        // p > 0.05  =>  v > m + log(0.05*s); margin 1e-3 >> logf error;
        // survivors re-tested below with the exact reference expression.
        thrv = __fsub_rn(__fadd_rn(m, logf(__fmul_rn(0.05f, s))), 1e-3f);
    }

    // ---- phase 3: re-read logits via laundered pointer (prevents CSE with
    // vals[]), test, emit survivors to LDS list.
    if (n < NBOX) {
        uintptr_t scu = (uintptr_t)sc;
        asm volatile("" : "+v"(scu));
        const float* scv = (const float*)scu;
        for (int c0 = 1; c0 < NCLS; c0 += 16) {
            float vt[16];
#pragma unroll
            for (int u = 0; u < 16; ++u) {
                int c = c0 + u;
                vt[u] = (c < NCLS) ? scv[(size_t)c * NBOX] : -1e30f;
            }
#pragma unroll
            for (int u = 0; u < 16; ++u) {
                int c = c0 + u;
                if (vt[u] > thrv) {
                    // exact test — identical expression to validated rounds
                    float p = __fdiv_rn(expf(__fsub_rn(vt[u], m)), s);
                    if (p > SCORE_THR) {
                        int e = atomicAdd(&lcnt, 1);
                        if (e < LCAP)
                            list[e] = ((unsigned long long)__float_as_uint(p) << 32) |
                                      ((unsigned long long)(unsigned)(c - 1) << 24) |
                                      (unsigned long long)(unsigned)n;
                    }
                }
            }
        }
    }
    __syncthreads();

    const int E = min(lcnt, LCAP);

    // ---- phase 4: per-class histogram (LDS atomics)
    for (int i = tid; i < E; i += 256) {
        int c = (int)((list[i] >> 24) & 0xFF);
        atomicAdd(&ccnt[c], 1);
    }
    __syncthreads();

    // ---- phase 5: one global atomic per (block, class) to reserve ranges
    if (tid < NFG && ccnt[tid] > 0)
        cbase[tid] = atomicAdd(&gcnt[b * NFG + tid], ccnt[tid]);
    __syncthreads();
    if (tid < NFG) ccnt[tid] = 0;   // reuse as cursor
    __syncthreads();

    // ---- phase 6: scatter entries to reserved slots
    for (int i = tid; i < E; i += 256) {
        unsigned long long e = list[i];
        int c = (int)((e >> 24) & 0xFF);
        unsigned nn = (unsigned)(e & 0xFFFFFF);
        int pos = cbase[c] + atomicAdd(&ccnt[c], 1);
        if (pos < GCAP) {
            unsigned pb = (unsigned)(e >> 32);
            gcand[(size_t)(b * NFG + c) * GCAP + pos] =
                ((unsigned long long)pb << 32) |
                (unsigned long long)(0xFFFFFFFFu - nn);
        }
    }
}

// ---------------------------------------------------------------- K2: per-(image,class) select + sort + NMS
// ROUND-7 LESSON: k2 is VALU-bound; sorting 512 slots to keep 200 is ~40%
// of its VALU ops. Exact select-then-sort: binary search on p_bits finds
// T0 with #{>=T0} in [200,256]; survivors strictly dominate discards in
// u64 order, so sorting 256 gives the identical top-200 sequence.
__global__ __launch_bounds__(256) void k2_nms(
    const unsigned long long* __restrict__ gcand,  // [NTASK*GCAP]
    const int* __restrict__ gcnt,                  // [NTASK]
    const float4* __restrict__ ltrb,               // [B*N]
    float* __restrict__ cls_scores,                // [NTASK*200]
    int* __restrict__ cls_idx)                     // [NTASK*200] global ltrb index
{
    const int t = blockIdx.x;       // task = b*80 + (c-1)
    const int b = t / NFG;
    const int tid = threadIdx.x;

    // cand is dead after Phase C; mrow aliases it (saves 6.4 KB LDS)
    __shared__ unsigned long long cand[SORTCAP];                     // 8 KB
    unsigned long long (*mrow)[4] = (unsigned long long(*)[4])cand;  // [200][4]
    __shared__ float4 sbox[TOPK];
    __shared__ float sarea[TOPK];
    __shared__ float sscore[TOPK];
    __shared__ int sidx[TOPK];
    __shared__ unsigned long long keepw[4];
    __shared__ int wsum[4];
    __shared__ int scat;

    const int cl = min(gcnt[t], SORTCAP);

    // load all candidates into registers (4/thread)
    const unsigned long long* gc = gcand + (size_t)t * GCAP;
    unsigned long long myc[4];
    unsigned myhi[4];
#pragma unroll
    for (int u = 0; u < 4; ++u) {
        int i = tid + u * 256;
        myc[u] = (i < cl) ? gc[i] : 0ULL;
        myhi[u] = (unsigned)(myc[u] >> 32);
    }

    // ---- selection: binary search T0 on p_bits so that #{>=T0} in [200,256]
    bool doSel = (cl > 256);
    int selN = cl;
    unsigned T0 = 0;
    if (doSel) {
        unsigned lo = 0x3D000000u, hi = 0x3F800000u;   // p in (0.05, 1.0]
        while (lo < hi) {
            unsigned mid = lo + ((hi - lo + 1) >> 1);
            int c2 = 0;
#pragma unroll
            for (int u = 0; u < 4; ++u) c2 += (myhi[u] >= mid) ? 1 : 0;
#pragma unroll
            for (int s2 = 1; s2 < 64; s2 <<= 1) c2 += __shfl_xor(c2, s2);
            if ((tid & 63) == 0) wsum[tid >> 6] = c2;
            __syncthreads();
            int tot = wsum[0] + wsum[1] + wsum[2] + wsum[3];
            __syncthreads();
            if (tot >= TOPK) lo = mid; else hi = mid - 1;
        }
        T0 = lo;
        int c2 = 0;
#pragma unroll
        for (int u = 0; u < 4; ++u) c2 += (myhi[u] >= T0) ? 1 : 0;
#pragma unroll
        for (int s2 = 1; s2 < 64; s2 <<= 1) c2 += __shfl_xor(c2, s2);
        if ((tid & 63) == 0) wsum[tid >> 6] = c2;
        __syncthreads();
        selN = wsum[0] + wsum[1] + wsum[2] + wsum[3];
        if (tid == 0) scat = 0;
        __syncthreads();
        if (selN > 256) doSel = false;  // tie explosion (needs 57+ identical p) -> full sort
    }

    unsigned nsort;
    if (doSel) {
        // compact survivors (order arbitrary; keys unique; sort canonicalizes)
#pragma unroll
        for (int u = 0; u < 4; ++u) {
            if (tid + u * 256 < cl && myhi[u] >= T0) {
                int pos = atomicAdd(&scat, 1);
                cand[pos] = myc[u];
            }
        }
        __syncthreads();
        for (int i = selN + tid; i < 256; i += 256) cand[i] = 0ULL;
        nsort = 256;
    } else {
#pragma unroll
        for (int u = 0; u < 4; ++u) cand[tid + u * 256] = myc[u];
        nsort = 2;
        while (nsort < (unsigned)cl) nsort <<= 1;
    }
    __syncthreads();

    // Phase B: bitonic sort descending (score desc, idx asc) — keys unique => deterministic
    for (unsigned k = 2; k <= nsort; k <<= 1) {
        for (unsigned j = k >> 1; j > 0; j >>= 1) {
            for (unsigned i = tid; i < nsort; i += 256) {
                unsigned ixj = i ^ j;
                if (ixj > i) {
                    unsigned long long a = cand[i], bb2 = cand[ixj];
                    bool desc = ((i & k) == 0);
                    if (desc ? (a < bb2) : (a > bb2)) { cand[i] = bb2; cand[ixj] = a; }
                }
            }
            __syncthreads();
        }
    }

    const int mk = min(cl, TOPK);

    // Phase C: gather boxes for top-mk (cand dead after this)
    if (tid < mk) {
        unsigned long long key = cand[tid];
        unsigned n = 0xFFFFFFFFu - (unsigned)(key & 0xFFFFFFFFull);
        float4 bx = ltrb[(size_t)b * NBOX + n];
        sbox[tid] = bx;
        sarea[tid] = __fmul_rn(__fsub_rn(bx.z, bx.x), __fsub_rn(bx.w, bx.y));
        sscore[tid] = __uint_as_float((unsigned)(key >> 32));
        sidx[tid] = b * NBOX + (int)n;
    }
    __syncthreads();

    // Phase D: suppression bitmask rows (IoU replicates reference's unclamped deltas)
    if (tid < mk) {
        float4 bi = sbox[tid];
        float ai = sarea[tid];
#pragma unroll
        for (int q = 0; q < 4; ++q) {
            unsigned long long w = 0ULL;
            int j0 = q * 64;
            int j1 = min(mk, j0 + 64);
            for (int j2 = max(tid + 1, j0); j2 < j1; ++j2) {
                float4 bj = sbox[j2];
                float ltx = fmaxf(bi.x, bj.x), lty = fmaxf(bi.y, bj.y);
                float rbx = fminf(bi.z, bj.z), rby = fminf(bi.w, bj.w);
                float dx = __fsub_rn(rbx, ltx), dy = __fsub_rn(rby, lty);
                float inter = __fmul_rn(dx, dy);
                float uni = __fsub_rn(__fadd_rn(ai, sarea[j2]), inter);
                float iou = __fdiv_rn(inter, uni);
                if (iou >= CRITERIA) w |= 1ULL << (j2 - j0);
            }
            mrow[tid][q] = w;
        }
    }
    __syncthreads();

    // Phase E: greedy sequential pass (thread 0, LDS prefetch one row ahead)
    if (tid == 0) {
        auto maskBits = [](int r) -> unsigned long long {
            if (r <= 0) return 0ULL;
            if (r >= 64) return ~0ULL;
            return (1ULL << r) - 1ULL;
        };
        unsigned long long kw0 = maskBits(mk);
        unsigned long long kw1 = maskBits(mk - 64);
        unsigned long long kw2 = maskBits(mk - 128);
        unsigned long long kw3 = maskBits(mk - 192);
        unsigned long long r0 = 0, r1 = 0, r2 = 0, r3 = 0;
        if (mk > 0) { r0 = mrow[0][0]; r1 = mrow[0][1]; r2 = mrow[0][2]; r3 = mrow[0][3]; }
#define GREEDY_WORD(KW, BASE)                                                     \
        for (int bit2 = 0; bit2 < 64; ++bit2) {                                   \
            int i = (BASE) + bit2;                                                \
            if (i >= mk) break;                                                   \
            int ip = (i + 1 < mk) ? (i + 1) : i;                                  \
            unsigned long long n0 = mrow[ip][0], n1 = mrow[ip][1],                \
                               n2 = mrow[ip][2], n3 = mrow[ip][3];                \
            if ((KW >> bit2) & 1ULL) {                                            \
                kw0 &= ~r0; kw1 &= ~r1; kw2 &= ~r2; kw3 &= ~r3;                   \
            }                                                                     \
            r0 = n0; r1 = n1; r2 = n2; r3 = n3;                                   \
        }
        GREEDY_WORD(kw0, 0)
        GREEDY_WORD(kw1, 64)
        GREEDY_WORD(kw2, 128)
        GREEDY_WORD(kw3, 192)
#undef GREEDY_WORD
        keepw[0] = kw0; keepw[1] = kw1; keepw[2] = kw2; keepw[3] = kw3;
    }
    __syncthreads();

    // Phase F: write per-class results
    if (tid < TOPK) {
        float s = NEG_INF;
        if (tid < mk && ((keepw[tid >> 6] >> (tid & 63)) & 1ULL)) s = sscore[tid];
        cls_scores[(size_t)t * TOPK + tid] = s;
        if (tid < mk) cls_idx[(size_t)t * TOPK + tid] = sidx[tid];
    }
}

// ---------------------------------------------------------------- K3: per-image global top-200
__device__ __forceinline__ int blockReduceSum(int x, int* red, int tid) {
    __syncthreads();
    red[tid] = x;
    __syncthreads();
    for (int off = 128; off > 0; off >>= 1) {
        if (tid < off) red[tid] += red[tid + off];
        __syncthreads();
    }
    return red[0];
}

__global__ __launch_bounds__(256) void k3_topk(
    const float* __restrict__ cls_scores,   // [B*80*200]
    const int* __restrict__ cls_idx,        // [B*80*200]
    const float4* __restrict__ ltrb,        // [B*N]
    float* __restrict__ out)
{
    const int b = blockIdx.x;
    const int tid = threadIdx.x;
    const int NFLAT = NFG * TOPK;           // 16000
    const int PER = 63;

    __shared__ unsigned long long sel[512];
    __shared__ int scnt;
    __shared__ int red[256];

    const float* S = cls_scores + (size_t)b * NFLAT;
    float v[PER];
#pragma unroll
    for (int i = 0; i < PER; ++i) {
        int j = i * 256 + tid;
        v[i] = (j < NFLAT) ? S[j] : NEG_INF;
    }

    int lc = 0;
#pragma unroll
    for (int i = 0; i < PER; ++i) lc += (v[i] > -1e29f) ? 1 : 0;
    int validCount = blockReduceSum(lc, red, tid);

    unsigned thrBits = 0;
    if (validCount > TOPK) {
        unsigned lo = 0, hi = 0x7F800000u;
        while (lo < hi) {
            unsigned mid = (lo + hi) >> 1;
            float mf = __uint_as_float(mid);
            int c2 = 0;
#pragma unroll
            for (int i = 0; i < PER; ++i) c2 += (v[i] > mf) ? 1 : 0;
            int tot = blockReduceSum(c2, red, tid);
            if (tot < TOPK) hi = mid; else lo = mid + 1;
        }
        thrBits = lo;
    }

    __syncthreads();
    if (tid == 0) scnt = 0;
    for (int i = tid; i < 512; i += 256) sel[i] = 0ULL;
    __syncthreads();

    const bool useGE = (validCount > TOPK);
    const float thrF = __uint_as_float(thrBits);
#pragma unroll
    for (int i = 0; i < PER; ++i) {
        int j = i * 256 + tid;
        bool take = useGE ? (v[i] >= thrF) : (v[i] > -1e29f);
        if (j < NFLAT && take) {
            int pos = atomicAdd(&scnt, 1);
            if (pos < 512) {
                sel[pos] = ((unsigned long long)__float_as_uint(v[i]) << 32) |
                           (unsigned long long)(0xFFFFFFFFu - (unsigned)j);
            }
        }
    }
    __syncthreads();
    int total = min(min(scnt, 512), TOPK);

    for (unsigned k = 2; k <= 512; k <<= 1) {
        for (unsigned j = k >> 1; j > 0; j >>= 1) {
            for (unsigned i = tid; i < 512; i += 256) {
                unsigned ixj = i ^ j;
                if (ixj > i) {
                    unsigned long long a = sel[i], bb2 = sel[ixj];
                    bool desc = ((i & k) == 0);
                    if (desc ? (a < bb2) : (a > bb2)) { sel[i] = bb2; sel[ixj] = a; }
                }
            }
            __syncthreads();
        }
    }

    if (tid < TOPK) {
        size_t ob = (size_t)b * TOPK + tid;
        float4 bx = make_float4(0.f, 0.f, 0.f, 0.f);
        float lab = 0.f, sc2 = 0.f;
        if (tid < total) {
            unsigned long long key = sel[tid];
            unsigned j = 0xFFFFFFFFu - (unsigned)(key & 0xFFFFFFFFull);
            sc2 = __uint_as_float((unsigned)(key >> 32));
            unsigned cls = j / TOPK;
            int gi = cls_idx[(size_t)b * NFLAT + j];
            bx = ltrb[gi];
            lab = (float)(cls + 1);
        }
        reinterpret_cast<float4*>(out)[ob] = bx;
        out[(size_t)BATCH * TOPK * 4 + ob] = lab;
        out[(size_t)BATCH * TOPK * 4 + (size_t)BATCH * TOPK + ob] = sc2;
    }
}

// ---------------------------------------------------------------- launch
extern "C" void kernel_launch(void* const* d_in, const int* in_sizes, int n_in,
                              void* d_out, int out_size, void* d_ws, size_t ws_size,
                              hipStream_t stream) {
    (void)in_sizes; (void)n_in; (void)out_size; (void)ws_size;
    const float* bboxes = (const float*)d_in[0];   // [32,4,15130]
    const float* scores = (const float*)d_in[1];   // [32,81,15130]
    const float* dboxes = (const float*)d_in[2];   // [1,15130,4]
    float* out = (float*)d_out;

    char* ws = (char*)d_ws;
    size_t off = 0;
    float4* ltrb = (float4*)(ws + off);      off += (size_t)BATCH * NBOX * 16;    //  7,746,560
    unsigned long long* gcand = (unsigned long long*)(ws + off);
                                             off += (size_t)NTASK * GCAP * 8;     // 20,971,520
    float* cls_scores = (float*)(ws + off);  off += (size_t)NTASK * TOPK * 4;     //  2,048,000
    int*   cls_idx    = (int*)(ws + off);    off += (size_t)NTASK * TOPK * 4;     //  2,048,000
    int*   gcnt       = (int*)(ws + off);    off += (size_t)NTASK * 4;            //     10,240

    hipMemsetAsync(gcnt, 0, NTASK * sizeof(int), stream);

    k1_fused<<<BATCH * NCHUNK, 256, 0, stream>>>(bboxes, scores, dboxes, ltrb, gcand, gcnt);
    k2_nms<<<NTASK, 256, 0, stream>>>(gcand, gcnt, ltrb, cls_scores, cls_idx);
    k3_topk<<<BATCH, 256, 0, stream>>>(cls_scores, cls_idx, ltrb, out);
}

// Round 9
// 231.677 us; speedup vs baseline: 1.1450x; 1.1450x over previous
//
#include <hip/hip_runtime.h>
#include <cstdint>
#include <cstddef>

#define BATCH 32
#define NCLS 81
#define NFG 80
#define NBOX 15130
#define NCHUNK 60         // ceil(15130/256)
#define TOPK 200
#define NTASK (BATCH * NFG)
#define NEG_INF -1e30f
#define GCAP 1024         // per-task candidate capacity (measured mean ~434)
#define SORTCAP 1024
#define LCAP 4864         // 256 boxes * max 19 classes/box (hard bound: sum p = 1)
#define SCORE_THR 0.05f
#define CRITERIA 0.45f

// ---------------------------------------------------------------- K1: decode + softmax + compacted candidate emission
// ROUND-2 LESSON: vals[81] must be DEAD after the sum loop; the phase-3
// re-read goes through an asm-laundered pointer so the compiler cannot CSE
// it back to vals[] and extend liveness (spill -> 990 us).
// ROUND-3 LESSON: no per-element global atomics on few hot addresses
// (1900 us). Emission batches ONE global atomicAdd per (block,class).
// ROUND-4/5/6 LESSON: per-(b,c) blocks must not re-stream 60 KB each from
// the L2-miss path (~115 us floor); k2 reads ~3.5 KB compacted lists.
__global__ __launch_bounds__(256) void k1_fused(
    const float* __restrict__ bboxes,   // [B,4,N]
    const float* __restrict__ scores,   // [B,C,N]
    const float* __restrict__ dboxes,   // [N,4]
    float4* __restrict__ ltrb,          // [B*N]
    unsigned long long* __restrict__ gcand,  // [NTASK*GCAP]
    int* __restrict__ gcnt)             // [NTASK] (zeroed before launch)
{
    const int blk = blockIdx.x;
    const int b = blk / NCHUNK;
    const int chunk = blk - b * NCHUNK;
    const int tid = threadIdx.x;
    const int n = chunk * 256 + tid;

    __shared__ unsigned long long list[LCAP];   // (p_bits<<32)|(cfg<<24)|n
    __shared__ int lcnt;
    __shared__ int ccnt[NFG];
    __shared__ int cbase[NFG];

    if (tid == 0) lcnt = 0;
    if (tid < NFG) ccnt[tid] = 0;
    __syncthreads();

    float m = 0.f, s = 1.f, thrv = 1e30f;
    const float* sc = scores;           // set properly below when n valid

    if (n < NBOX) {
        // ---- decode (bit-exact, validated rounds 1-8)
        const float* bb = bboxes + (size_t)b * 4 * NBOX + n;
        float bx = bb[0];
        float by = bb[NBOX];
        float bw = bb[2 * (size_t)NBOX];
        float bh = bb[3 * (size_t)NBOX];
        float4 d = reinterpret_cast<const float4*>(dboxes)[n];  // cx, cy, w, h
        float xx = __fadd_rn(__fmul_rn(__fmul_rn(0.1f, bx), d.z), d.x);
        float yy = __fadd_rn(__fmul_rn(__fmul_rn(0.1f, by), d.w), d.y);
        float wx = __fmul_rn(expf(__fmul_rn(0.2f, bw)), d.z);
        float wy = __fmul_rn(expf(__fmul_rn(0.2f, bh)), d.w);
        float4 o;
        o.x = __fsub_rn(xx, __fmul_rn(0.5f, wx));
        o.y = __fsub_rn(yy, __fmul_rn(0.5f, wy));
        o.z = __fadd_rn(xx, __fmul_rn(0.5f, wx));
        o.w = __fadd_rn(yy, __fmul_rn(0.5f, wy));
        ltrb[(size_t)b * NBOX + n] = o;

        // ---- softmax stats (vals[] dead after this scope; sequential sum
        // order must stay EXACT — bit-identical p has held absmax 0.0)
        sc = scores + (size_t)b * NCLS * NBOX + n;
        {
            float vals[NCLS];
#pragma unroll
            for (int c = 0; c < NCLS; ++c) vals[c] = sc[(size_t)c * NBOX];
            m = vals[0];
#pragma unroll
            for (int c = 1; c < NCLS; ++c) m = fmaxf(m, vals[c]);
            float ss = 0.0f;
#pragma unroll
            for (int c = 0; c < NCLS; ++c) ss = __fadd_rn(ss, expf(__fsub_rn(vals[c], m)));
            s = ss;
        }
        // p > 0.05  =>  v > m + log(0.05*s); margin 1e-3 >> logf error;
        // survivors re-tested below with the exact reference expression.
        thrv = __fsub_rn(__fadd_rn(m, logf(__fmul_rn(0.05f, s))), 1e-3f);
    }

    // ---- phase 3: re-read logits via laundered pointer (prevents CSE with
    // vals[]), test, emit survivors to LDS list.
    if (n < NBOX) {
        uintptr_t scu = (uintptr_t)sc;
        asm volatile("" : "+v"(scu));
        const float* scv = (const float*)scu;
        for (int c0 = 1; c0 < NCLS; c0 += 16) {
            float vt[16];
#pragma unroll
            for (int u = 0; u < 16; ++u) {
                int c = c0 + u;
                vt[u] = (c < NCLS) ? scv[(size_t)c * NBOX] : -1e30f;
            }
#pragma unroll
            for (int u = 0; u < 16; ++u) {
                int c = c0 + u;
                if (vt[u] > thrv) {
                    // exact test — identical expression to validated rounds
                    float p = __fdiv_rn(expf(__fsub_rn(vt[u], m)), s);
                    if (p > SCORE_THR) {
                        int e = atomicAdd(&lcnt, 1);
                        if (e < LCAP)
                            list[e] = ((unsigned long long)__float_as_uint(p) << 32) |
                                      ((unsigned long long)(unsigned)(c - 1) << 24) |
                                      (unsigned long long)(unsigned)n;
                    }
                }
            }
        }
    }
    __syncthreads();

    const int E = min(lcnt, LCAP);

    // ---- phase 4: per-class histogram (LDS atomics)
    for (int i = tid; i < E; i += 256) {
        int c = (int)((list[i] >> 24) & 0xFF);
        atomicAdd(&ccnt[c], 1);
    }
    __syncthreads();

    // ---- phase 5: one global atomic per (block, class) to reserve ranges
    if (tid < NFG && ccnt[tid] > 0)
        cbase[tid] = atomicAdd(&gcnt[b * NFG + tid], ccnt[tid]);
    __syncthreads();
    if (tid < NFG) ccnt[tid] = 0;   // reuse as cursor
    __syncthreads();

    // ---- phase 6: scatter entries to reserved slots
    for (int i = tid; i < E; i += 256) {
        unsigned long long e = list[i];
        int c = (int)((e >> 24) & 0xFF);
        unsigned nn = (unsigned)(e & 0xFFFFFF);
        int pos = cbase[c] + atomicAdd(&ccnt[c], 1);
        if (pos < GCAP) {
            unsigned pb = (unsigned)(e >> 32);
            gcand[(size_t)(b * NFG + c) * GCAP + pos] =
                ((unsigned long long)pb << 32) |
                (unsigned long long)(0xFFFFFFFFu - nn);
        }
    }
}

// ---------------------------------------------------------------- register bitonic sort (1024 items, 16/lane, no barriers)
// Compile-time network: j>=64 -> register-pair swap; j<64 -> shfl_xor.
// All register indices are compile-time (rule #20: no scratch).
template<int J, int K>
__device__ __forceinline__ void bstep(unsigned long long (&it)[16], const int lane) {
    if constexpr (J >= 64) {
        constexpr int M = J >> 6;
#pragma unroll
        for (int r = 0; r < 16; ++r) {
            const int rp = r ^ M;
            if (rp > r) {
                const bool desc = (((unsigned)(r << 6) & (unsigned)K) == 0u);
                unsigned long long a = it[r], bb = it[rp];
                if (desc ? (a < bb) : (a > bb)) { it[r] = bb; it[rp] = a; }
            }
        }
    } else {
#pragma unroll
        for (int r = 0; r < 16; ++r) {
            unsigned long long a = it[r];
            unsigned long long bb = __shfl_xor(a, J, 64);
            const unsigned i = ((unsigned)(r << 6)) | (unsigned)lane;
            const bool desc = ((i & (unsigned)K) == 0u);
            const bool lower = ((lane & J) == 0);
            it[r] = ((desc == lower) ? (a >= bb) : (a <= bb)) ? a : bb;
        }
    }
}

template<int K, int J>
__device__ __forceinline__ void bstage(unsigned long long (&it)[16], const int lane) {
    bstep<J, K>(it, lane);
    if constexpr (J > 1) bstage<K, (J >> 1)>(it, lane);
}

// ---------------------------------------------------------------- K2: one wave per (image,class): reg-sort + fused greedy NMS
// ROUND-7/8 LESSON: k2 was barrier-latency bound (45+ barriered LDS sort
// passes + serial mask build + serial greedy). One wave per task removes
// every barrier; suppression is computed ON DEMAND only for boxes still
// alive when reached (same comparisons, same greedy order as reference).
__global__ __launch_bounds__(64) void k2_nms(
    const unsigned long long* __restrict__ gcand,  // [NTASK*GCAP]
    const int* __restrict__ gcnt,                  // [NTASK]
    const float4* __restrict__ ltrb,               // [B*N]
    float* __restrict__ cls_scores,                // [NTASK*200]
    int* __restrict__ cls_idx)                     // [NTASK*200] global ltrb index
{
    const int t = blockIdx.x;       // task = b*80 + (c-1)
    const int b = t / NFG;
    const int lane = threadIdx.x;   // 0..63

    __shared__ float4 sbox[TOPK];
    __shared__ float sarea[TOPK];

    const int cl = min(gcnt[t], SORTCAP);
    const unsigned long long* gc = gcand + (size_t)t * GCAP;

    // load 16 items/lane: it[r] holds item index i = r*64+lane
    unsigned long long it[16];
#pragma unroll
    for (int r = 0; r < 16; ++r) {
        const int i = (r << 6) + lane;
        it[r] = (i < cl) ? gc[i] : 0ULL;
    }

    // sort descending to next_pow2(cl); zero-pad tail stays sorted-after
    unsigned kmax = 2;
    while (kmax < (unsigned)cl) kmax <<= 1;

    bstage<2, 1>(it, lane);
    if (kmax >= 4)    bstage<4, 2>(it, lane);
    if (kmax >= 8)    bstage<8, 4>(it, lane);
    if (kmax >= 16)   bstage<16, 8>(it, lane);
    if (kmax >= 32)   bstage<32, 16>(it, lane);
    if (kmax >= 64)   bstage<64, 32>(it, lane);
    if (kmax >= 128)  bstage<128, 64>(it, lane);
    if (kmax >= 256)  bstage<256, 128>(it, lane);
    if (kmax >= 512)  bstage<512, 256>(it, lane);
    if (kmax >= 1024) bstage<1024, 512>(it, lane);

    const int mk = min(cl, TOPK);

    // gather top-mk boxes; lane owns items/cols i = r*64+lane, r<4
    float4 myb[4];
    float mya[4], myp[4];
    int myn[4];
#pragma unroll
    for (int r = 0; r < 4; ++r) {
        const int i = (r << 6) + lane;
        myb[r] = make_float4(0.f, 0.f, 0.f, 0.f);
        mya[r] = 0.f; myp[r] = 0.f; myn[r] = 0;
        if (i < mk) {
            const unsigned long long key = it[r];
            const unsigned n = 0xFFFFFFFFu - (unsigned)(key & 0xFFFFFFFFull);
            const float4 bx = ltrb[(size_t)b * NBOX + n];
            myb[r] = bx;
            mya[r] = __fmul_rn(__fsub_rn(bx.z, bx.x), __fsub_rn(bx.w, bx.y));
            myp[r] = __uint_as_float((unsigned)(key >> 32));
            myn[r] = b * NBOX + (int)n;
            sbox[i] = bx;
            sarea[i] = mya[r];
        }
    }
    __syncthreads();    // 1 wave: cheap (waitcnt + immediate barrier)

    // fused greedy NMS: serial over sorted i; all lanes keep identical kw
    // (ballot result is uniform). Suppressed rows cost only the bit test.
    // IoU replicates reference's unclamped deltas; identical FP expressions.
    auto maskBits = [](int r) -> unsigned long long {
        if (r <= 0) return 0ULL;
        if (r >= 64) return ~0ULL;
        return (1ULL << r) - 1ULL;
    };
    unsigned long long kw0 = maskBits(mk);
    unsigned long long kw1 = maskBits(mk - 64);
    unsigned long long kw2 = maskBits(mk - 128);
    unsigned long long kw3 = maskBits(mk - 192);

#define NMS_QUAD(KWQ, Q)                                                           \
    {                                                                              \
        const int i0 = (Q) << 6;                                                   \
        const int i1 = min(mk, i0 + 64);                                           \
        for (int i = i0; i < i1; ++i) {                                            \
            if ((KWQ >> (i - i0)) & 1ULL) {                                        \
                const float4 bi = sbox[i];                                         \
                const float ai = sarea[i];                                         \
                _Pragma("unroll")                                                  \
                for (int q2 = 0; q2 < 4; ++q2) {                                   \
                    const int j = (q2 << 6) + lane;                                \
                    const float4 bj = myb[q2];                                     \
                    const float ltx = fmaxf(bi.x, bj.x), lty = fmaxf(bi.y, bj.y);  \
                    const float rbx = fminf(bi.z, bj.z), rby = fminf(bi.w, bj.w);  \
                    const float dx = __fsub_rn(rbx, ltx), dy = __fsub_rn(rby, lty);\
                    const float inter = __fmul_rn(dx, dy);                         \
                    const float uni = __fsub_rn(__fadd_rn(ai, mya[q2]), inter);    \
                    const float iou = __fdiv_rn(inter, uni);                       \
                    const unsigned long long sup =                                 \
                        __ballot((iou >= CRITERIA) && (j > i));                    \
                    if (q2 == 0) kw0 &= ~sup;                                      \
                    else if (q2 == 1) kw1 &= ~sup;                                 \
                    else if (q2 == 2) kw2 &= ~sup;                                 \
                    else kw3 &= ~sup;                                              \
                }                                                                  \
            }                                                                      \
        }                                                                          \
    }
    NMS_QUAD(kw0, 0)
    NMS_QUAD(kw1, 1)
    NMS_QUAD(kw2, 2)
    NMS_QUAD(kw3, 3)
#undef NMS_QUAD

    // write per-class results (coalesced per r-group)
#pragma unroll
    for (int r = 0; r < 4; ++r) {
        const int i = (r << 6) + lane;
        if (i < TOPK) {
            const unsigned long long kq = (r == 0) ? kw0 : (r == 1) ? kw1
                                         : (r == 2) ? kw2 : kw3;
            const bool keep = (i < mk) && ((kq >> lane) & 1ULL);
            cls_scores[(size_t)t * TOPK + i] = keep ? myp[r] : NEG_INF;
            if (i < mk) cls_idx[(size_t)t * TOPK + i] = myn[r];
        }
    }
}

// ---------------------------------------------------------------- K3: per-image global top-200
__device__ __forceinline__ int blockReduceSum(int x, int* red, int tid) {
    __syncthreads();
    red[tid] = x;
    __syncthreads();
    for (int off = 128; off > 0; off >>= 1) {
        if (tid < off) red[tid] += red[tid + off];
        __syncthreads();
    }
    return red[0];
}

__global__ __launch_bounds__(256) void k3_topk(
    const float* __restrict__ cls_scores,   // [B*80*200]
    const int* __restrict__ cls_idx,        // [B*80*200]
    const float4* __restrict__ ltrb,        // [B*N]
    float* __restrict__ out)
{
    const int b = blockIdx.x;
    const int tid = threadIdx.x;
    const int NFLAT = NFG * TOPK;           // 16000
    const int PER = 63;

    __shared__ unsigned long long sel[512];
    __shared__ int scnt;
    __shared__ int red[256];

    const float* S = cls_scores + (size_t)b * NFLAT;
    float v[PER];
#pragma unroll
    for (int i = 0; i < PER; ++i) {
        int j = i * 256 + tid;
        v[i] = (j < NFLAT) ? S[j] : NEG_INF;
    }

    int lc = 0;
#pragma unroll
    for (int i = 0; i < PER; ++i) lc += (v[i] > -1e29f) ? 1 : 0;
    int validCount = blockReduceSum(lc, red, tid);

    unsigned thrBits = 0;
    if (validCount > TOPK) {
        unsigned lo = 0, hi = 0x7F800000u;
        while (lo < hi) {
            unsigned mid = (lo + hi) >> 1;
            float mf = __uint_as_float(mid);
            int c2 = 0;
#pragma unroll
            for (int i = 0; i < PER; ++i) c2 += (v[i] > mf) ? 1 : 0;
            int tot = blockReduceSum(c2, red, tid);
            if (tot < TOPK) hi = mid; else lo = mid + 1;
        }
        thrBits = lo;
    }

    __syncthreads();
    if (tid == 0) scnt = 0;
    for (int i = tid; i < 512; i += 256) sel[i] = 0ULL;
    __syncthreads();

    const bool useGE = (validCount > TOPK);
    const float thrF = __uint_as_float(thrBits);
#pragma unroll
    for (int i = 0; i < PER; ++i) {
        int j = i * 256 + tid;
        bool take = useGE ? (v[i] >= thrF) : (v[i] > -1e29f);
        if (j < NFLAT && take) {
            int pos = atomicAdd(&scnt, 1);
            if (pos < 512) {
                sel[pos] = ((unsigned long long)__float_as_uint(v[i]) << 32) |
                           (unsigned long long)(0xFFFFFFFFu - (unsigned)j);
            }
        }
    }
    __syncthreads();
    int total = min(min(scnt, 512), TOPK);

    for (unsigned k = 2; k <= 512; k <<= 1) {
        for (unsigned j = k >> 1; j > 0; j >>= 1) {
            for (unsigned i = tid; i < 512; i += 256) {
                unsigned ixj = i ^ j;
                if (ixj > i) {
                    unsigned long long a = sel[i], bb2 = sel[ixj];
                    bool desc = ((i & k) == 0);
                    if (desc ? (a < bb2) : (a > bb2)) { sel[i] = bb2; sel[ixj] = a; }
                }
            }
            __syncthreads();
        }
    }

    if (tid < TOPK) {
        size_t ob = (size_t)b * TOPK + tid;
        float4 bx = make_float4(0.f, 0.f, 0.f, 0.f);
        float lab = 0.f, sc2 = 0.f;
        if (tid < total) {
            unsigned long long key = sel[tid];
            unsigned j = 0xFFFFFFFFu - (unsigned)(key & 0xFFFFFFFFull);
            sc2 = __uint_as_float((unsigned)(key >> 32));
            unsigned cls = j / TOPK;
            int gi = cls_idx[(size_t)b * NFLAT + j];
            bx = ltrb[gi];
            lab = (float)(cls + 1);
        }
        reinterpret_cast<float4*>(out)[ob] = bx;
        out[(size_t)BATCH * TOPK * 4 + ob] = lab;
        out[(size_t)BATCH * TOPK * 4 + (size_t)BATCH * TOPK + ob] = sc2;
    }
}

// ---------------------------------------------------------------- launch
extern "C" void kernel_launch(void* const* d_in, const int* in_sizes, int n_in,
                              void* d_out, int out_size, void* d_ws, size_t ws_size,
                              hipStream_t stream) {
    (void)in_sizes; (void)n_in; (void)out_size; (void)ws_size;
    const float* bboxes = (const float*)d_in[0];   // [32,4,15130]
    const float* scores = (const float*)d_in[1];   // [32,81,15130]
    const float* dboxes = (const float*)d_in[2];   // [1,15130,4]
    float* out = (float*)d_out;

    char* ws = (char*)d_ws;
    size_t off = 0;
    float4* ltrb = (float4*)(ws + off);      off += (size_t)BATCH * NBOX * 16;    //  7,746,560
    unsigned long long* gcand = (unsigned long long*)(ws + off);
                                             off += (size_t)NTASK * GCAP * 8;     // 20,971,520
    float* cls_scores = (float*)(ws + off);  off += (size_t)NTASK * TOPK * 4;     //  2,048,000
    int*   cls_idx    = (int*)(ws + off);    off += (size_t)NTASK * TOPK * 4;     //  2,048,000
    int*   gcnt       = (int*)(ws + off);    off += (size_t)NTASK * 4;            //     10,240

    hipMemsetAsync(gcnt, 0, NTASK * sizeof(int), stream);

    k1_fused<<<BATCH * NCHUNK, 256, 0, stream>>>(bboxes, scores, dboxes, ltrb, gcand, gcnt);
    k2_nms<<<NTASK, 64, 0, stream>>>(gcand, gcnt, ltrb, cls_scores, cls_idx);
    k3_topk<<<BATCH, 256, 0, stream>>>(cls_scores, cls_idx, ltrb, out);
}

// Round 10
// 209.092 us; speedup vs baseline: 1.2687x; 1.1080x over previous
//
#include <hip/hip_runtime.h>
#include <cstdint>
#include <cstddef>

#define BATCH 32
#define NCLS 81
#define NFG 80
#define NBOX 15130
#define NCHUNK 60         // ceil(15130/256)
#define TOPK 200
#define NTASK (BATCH * NFG)
#define NEG_INF -1e30f
#define GCAP 1024         // per-task candidate capacity (measured mean ~434)
#define SORTCAP 1024
#define LCAP 1920         // per-chunk survivor list; measured E~590±30, hard fallback below
#define SCORE_THR 0.05f
#define CRITERIA 0.45f

// ---------------------------------------------------------------- K1: decode + softmax + compacted candidate emission
// ROUND-2 LESSON: vals[81] must be DEAD after the sum loop; the phase-3
// re-read goes through an asm-laundered pointer so the compiler cannot CSE
// it back to vals[] and extend liveness (spill -> 990 us).
// ROUND-3 LESSON: no per-element global atomics on few hot addresses
// (1900 us). Emission batches ONE global atomicAdd per (block,class).
// ROUND-4/5/6 LESSON: per-(b,c) blocks must not re-stream 60 KB each from
// the L2-miss path (~115 us floor); k2 reads ~3.5 KB compacted lists.
// ROUND-9 LESSON: LCAP 4864 (39 KB LDS) capped occupancy at 36%; 1920
// (15.4 KB) -> 8 blocks/CU. Overflow (never taken: E~590, bound needs
// mean 7.5 survivors/box vs 2.3 measured) falls back to direct global emit.
__global__ __launch_bounds__(256) void k1_fused(
    const float* __restrict__ bboxes,   // [B,4,N]
    const float* __restrict__ scores,   // [B,C,N]
    const float* __restrict__ dboxes,   // [N,4]
    float4* __restrict__ ltrb,          // [B*N]
    unsigned long long* __restrict__ gcand,  // [NTASK*GCAP]
    int* __restrict__ gcnt)             // [NTASK] (zeroed before launch)
{
    const int blk = blockIdx.x;
    const int b = blk / NCHUNK;
    const int chunk = blk - b * NCHUNK;
    const int tid = threadIdx.x;
    const int n = chunk * 256 + tid;

    __shared__ unsigned long long list[LCAP];   // (p_bits<<32)|(cfg<<24)|n
    __shared__ int lcnt;
    __shared__ int ccnt[NFG];
    __shared__ int cbase[NFG];

    if (tid == 0) lcnt = 0;
    if (tid < NFG) ccnt[tid] = 0;
    __syncthreads();

    float m = 0.f, s = 1.f, thrv = 1e30f;
    const float* sc = scores;           // set properly below when n valid

    if (n < NBOX) {
        // ---- decode (bit-exact, validated rounds 1-9)
        const float* bb = bboxes + (size_t)b * 4 * NBOX + n;
        float bx = bb[0];
        float by = bb[NBOX];
        float bw = bb[2 * (size_t)NBOX];
        float bh = bb[3 * (size_t)NBOX];
        float4 d = reinterpret_cast<const float4*>(dboxes)[n];  // cx, cy, w, h
        float xx = __fadd_rn(__fmul_rn(__fmul_rn(0.1f, bx), d.z), d.x);
        float yy = __fadd_rn(__fmul_rn(__fmul_rn(0.1f, by), d.w), d.y);
        float wx = __fmul_rn(expf(__fmul_rn(0.2f, bw)), d.z);
        float wy = __fmul_rn(expf(__fmul_rn(0.2f, bh)), d.w);
        float4 o;
        o.x = __fsub_rn(xx, __fmul_rn(0.5f, wx));
        o.y = __fsub_rn(yy, __fmul_rn(0.5f, wy));
        o.z = __fadd_rn(xx, __fmul_rn(0.5f, wx));
        o.w = __fadd_rn(yy, __fmul_rn(0.5f, wy));
        ltrb[(size_t)b * NBOX + n] = o;

        // ---- softmax stats (vals[] dead after this scope; sequential sum
        // order must stay EXACT — bit-identical p has held absmax 0.0)
        sc = scores + (size_t)b * NCLS * NBOX + n;
        {
            float vals[NCLS];
#pragma unroll
            for (int c = 0; c < NCLS; ++c) vals[c] = sc[(size_t)c * NBOX];
            m = vals[0];
#pragma unroll
            for (int c = 1; c < NCLS; ++c) m = fmaxf(m, vals[c]);
            float ss = 0.0f;
#pragma unroll
            for (int c = 0; c < NCLS; ++c) ss = __fadd_rn(ss, expf(__fsub_rn(vals[c], m)));
            s = ss;
        }
        // p > 0.05  =>  v > m + log(0.05*s); margin 1e-3 >> logf error;
        // survivors re-tested below with the exact reference expression.
        thrv = __fsub_rn(__fadd_rn(m, logf(__fmul_rn(0.05f, s))), 1e-3f);
    }

    // ---- phase 3: re-read logits via laundered pointer (prevents CSE with
    // vals[]), test, emit survivors to LDS list.
    if (n < NBOX) {
        uintptr_t scu = (uintptr_t)sc;
        asm volatile("" : "+v"(scu));
        const float* scv = (const float*)scu;
        for (int c0 = 1; c0 < NCLS; c0 += 16) {
            float vt[16];
#pragma unroll
            for (int u = 0; u < 16; ++u) {
                int c = c0 + u;
                vt[u] = (c < NCLS) ? scv[(size_t)c * NBOX] : -1e30f;
            }
#pragma unroll
            for (int u = 0; u < 16; ++u) {
                int c = c0 + u;
                if (vt[u] > thrv) {
                    // exact test — identical expression to validated rounds
                    float p = __fdiv_rn(expf(__fsub_rn(vt[u], m)), s);
                    if (p > SCORE_THR) {
                        int e = atomicAdd(&lcnt, 1);
                        if (e < LCAP) {
                            list[e] = ((unsigned long long)__float_as_uint(p) << 32) |
                                      ((unsigned long long)(unsigned)(c - 1) << 24) |
                                      (unsigned long long)(unsigned)n;
                        } else {
                            // overflow fallback (never taken on this data):
                            // direct per-entry global reservation
                            int pos = atomicAdd(&gcnt[b * NFG + (c - 1)], 1);
                            if (pos < GCAP)
                                gcand[(size_t)(b * NFG + (c - 1)) * GCAP + pos] =
                                    ((unsigned long long)__float_as_uint(p) << 32) |
                                    (unsigned long long)(0xFFFFFFFFu - (unsigned)n);
                        }
                    }
                }
            }
        }
    }
    __syncthreads();

    const int E = min(lcnt, LCAP);

    // ---- phase 4: per-class histogram (LDS atomics)
    for (int i = tid; i < E; i += 256) {
        int c = (int)((list[i] >> 24) & 0xFF);
        atomicAdd(&ccnt[c], 1);
    }
    __syncthreads();

    // ---- phase 5: one global atomic per (block, class) to reserve ranges
    if (tid < NFG && ccnt[tid] > 0)
        cbase[tid] = atomicAdd(&gcnt[b * NFG + tid], ccnt[tid]);
    __syncthreads();
    if (tid < NFG) ccnt[tid] = 0;   // reuse as cursor
    __syncthreads();

    // ---- phase 6: scatter entries to reserved slots
    for (int i = tid; i < E; i += 256) {
        unsigned long long e = list[i];
        int c = (int)((e >> 24) & 0xFF);
        unsigned nn = (unsigned)(e & 0xFFFFFF);
        int pos = cbase[c] + atomicAdd(&ccnt[c], 1);
        if (pos < GCAP) {
            unsigned pb = (unsigned)(e >> 32);
            gcand[(size_t)(b * NFG + c) * GCAP + pos] =
                ((unsigned long long)pb << 32) |
                (unsigned long long)(0xFFFFFFFFu - nn);
        }
    }
}

// ---------------------------------------------------------------- register bitonic sort (NR*64 items, NR/lane, no barriers)
// Compile-time network: j>=64 -> register-pair swap; j<64 -> shfl_xor.
// All register indices are compile-time (rule #20: no scratch).
// ROUND-10: NR sized to cl (4/8/16) — cl~434 uses the 512 network,
// halving the dependent-shfl chain vs the fixed 1024 network.
template<int NR, int J, int K>
__device__ __forceinline__ void bstep(unsigned long long (&it)[NR], const int lane) {
    if constexpr (J >= 64) {
        constexpr int M = J >> 6;
#pragma unroll
        for (int r = 0; r < NR; ++r) {
            const int rp = r ^ M;
            if (rp > r) {
                const bool desc = (((unsigned)(r << 6) & (unsigned)K) == 0u);
                unsigned long long a = it[r], bb = it[rp];
                if (desc ? (a < bb) : (a > bb)) { it[r] = bb; it[rp] = a; }
            }
        }
    } else {
#pragma unroll
        for (int r = 0; r < NR; ++r) {
            unsigned long long a = it[r];
            unsigned long long bb = __shfl_xor(a, J, 64);
            const unsigned i = ((unsigned)(r << 6)) | (unsigned)lane;
            const bool desc = ((i & (unsigned)K) == 0u);
            const bool lower = ((lane & J) == 0);
            it[r] = ((desc == lower) ? (a >= bb) : (a <= bb)) ? a : bb;
        }
    }
}

template<int NR, int K, int J>
__device__ __forceinline__ void bstage(unsigned long long (&it)[NR], const int lane) {
    bstep<NR, J, K>(it, lane);
    if constexpr (J > 1) bstage<NR, K, (J >> 1)>(it, lane);
}

template<int NR>
__device__ __forceinline__ void bsort(unsigned long long (&it)[NR], const int lane,
                                      const unsigned kmax) {
    bstage<NR, 2, 1>(it, lane);
    if (kmax >= 4)   bstage<NR, 4, 2>(it, lane);
    if (kmax >= 8)   bstage<NR, 8, 4>(it, lane);
    if (kmax >= 16)  bstage<NR, 16, 8>(it, lane);
    if (kmax >= 32)  bstage<NR, 32, 16>(it, lane);
    if (kmax >= 64)  bstage<NR, 64, 32>(it, lane);
    if constexpr (NR >= 4) {
        if (kmax >= 128) bstage<NR, 128, 64>(it, lane);
        if (kmax >= 256) bstage<NR, 256, 128>(it, lane);
    }
    if constexpr (NR >= 8)  { if (kmax >= 512)  bstage<NR, 512, 256>(it, lane); }
    if constexpr (NR >= 16) { if (kmax >= 1024) bstage<NR, 1024, 512>(it, lane); }
}

// ---------------------------------------------------------------- K2: one wave per (image,class): reg-sort + fused greedy NMS
// ROUND-7/8 LESSON: barrier-latency bound -> one wave, zero barriers.
// ROUND-9 LESSON: grid-limited occupancy (2.5 waves/SIMD) -> cut per-wave
// critical path: cl-sized sort network + prefetch-one-row-ahead NMS (the
// 120-cyc LDS read leaves the alive-row dependence chain).
__global__ __launch_bounds__(64) void k2_nms(
    const unsigned long long* __restrict__ gcand,  // [NTASK*GCAP]
    const int* __restrict__ gcnt,                  // [NTASK]
    const float4* __restrict__ ltrb,               // [B*N]
    float* __restrict__ cls_scores,                // [NTASK*200]
    int* __restrict__ cls_idx)                     // [NTASK*200] global ltrb index
{
    const int t = blockIdx.x;       // task = b*80 + (c-1)
    const int b = t / NFG;
    const int lane = threadIdx.x;   // 0..63

    __shared__ float4 sbox[TOPK];
    __shared__ float sarea[TOPK];

    const int cl = min(gcnt[t], SORTCAP);
    const unsigned long long* gc = gcand + (size_t)t * GCAP;

    unsigned kmax = 2;
    while (kmax < (unsigned)cl) kmax <<= 1;

    // sort descending into top4 (items 0..255 = r*64+lane, r<4)
    unsigned long long top4[4];
    if (cl <= 256) {
        unsigned long long it[4];
#pragma unroll
        for (int r = 0; r < 4; ++r) {
            const int i = (r << 6) + lane;
            it[r] = (i < cl) ? gc[i] : 0ULL;
        }
        bsort<4>(it, lane, kmax);
#pragma unroll
        for (int r = 0; r < 4; ++r) top4[r] = it[r];
    } else if (cl <= 512) {
        unsigned long long it[8];
#pragma unroll
        for (int r = 0; r < 8; ++r) {
            const int i = (r << 6) + lane;
            it[r] = (i < cl) ? gc[i] : 0ULL;
        }
        bsort<8>(it, lane, kmax);
#pragma unroll
        for (int r = 0; r < 4; ++r) top4[r] = it[r];
    } else {
        unsigned long long it[16];
#pragma unroll
        for (int r = 0; r < 16; ++r) {
            const int i = (r << 6) + lane;
            it[r] = (i < cl) ? gc[i] : 0ULL;
        }
        bsort<16>(it, lane, kmax);
#pragma unroll
        for (int r = 0; r < 4; ++r) top4[r] = it[r];
    }

    const int mk = min(cl, TOPK);

    // gather top-mk boxes; lane owns items/cols i = r*64+lane, r<4
    float4 myb[4];
    float mya[4], myp[4];
    int myn[4];
#pragma unroll
    for (int r = 0; r < 4; ++r) {
        const int i = (r << 6) + lane;
        myb[r] = make_float4(0.f, 0.f, 0.f, 0.f);
        mya[r] = 0.f; myp[r] = 0.f; myn[r] = 0;
        if (i < mk) {
            const unsigned long long key = top4[r];
            const unsigned n = 0xFFFFFFFFu - (unsigned)(key & 0xFFFFFFFFull);
            const float4 bx = ltrb[(size_t)b * NBOX + n];
            myb[r] = bx;
            mya[r] = __fmul_rn(__fsub_rn(bx.z, bx.x), __fsub_rn(bx.w, bx.y));
            myp[r] = __uint_as_float((unsigned)(key >> 32));
            myn[r] = b * NBOX + (int)n;
            sbox[i] = bx;
            sarea[i] = mya[r];
        }
    }
    __syncthreads();    // 1 wave: compiles to waitcnt + immediate barrier

    // fused greedy NMS: serial over sorted i; all lanes keep identical kw
    // (ballot result is uniform). Suppressed rows cost only the bit test.
    // Row i+1's box is PREFETCHED while row i is processed.
    // IoU replicates reference's unclamped deltas; identical FP expressions.
    auto maskBits = [](int r) -> unsigned long long {
        if (r <= 0) return 0ULL;
        if (r >= 64) return ~0ULL;
        return (1ULL << r) - 1ULL;
    };
    unsigned long long kw0 = maskBits(mk);
    unsigned long long kw1 = maskBits(mk - 64);
    unsigned long long kw2 = maskBits(mk - 128);
    unsigned long long kw3 = maskBits(mk - 192);

    float4 nb = sbox[0];
    float na = sarea[0];

#define NMS_QUAD(KWQ, Q)                                                           \
    {                                                                              \
        const int i0 = (Q) << 6;                                                   \
        const int i1 = min(mk, i0 + 64);                                           \
        for (int i = i0; i < i1; ++i) {                                            \
            const float4 bi = nb;                                                  \
            const float ai = na;                                                   \
            const int ip = min(i + 1, TOPK - 1);                                   \
            nb = sbox[ip];                                                         \
            na = sarea[ip];                                                        \
            if ((KWQ >> (i - i0)) & 1ULL) {                                        \
                _Pragma("unroll")                                                  \
                for (int q2 = 0; q2 < 4; ++q2) {                                   \
                    const int j = (q2 << 6) + lane;                                \
                    const float4 bj = myb[q2];                                     \
                    const float ltx = fmaxf(bi.x, bj.x), lty = fmaxf(bi.y, bj.y);  \
                    const float rbx = fminf(bi.z, bj.z), rby = fminf(bi.w, bj.w);  \
                    const float dx = __fsub_rn(rbx, ltx), dy = __fsub_rn(rby, lty);\
                    const float inter = __fmul_rn(dx, dy);                         \
                    const float uni = __fsub_rn(__fadd_rn(ai, mya[q2]), inter);    \
                    const float iou = __fdiv_rn(inter, uni);                       \
                    const unsigned long long sup =                                 \
                        __ballot((iou >= CRITERIA) && (j > i));                    \
                    if (q2 == 0) kw0 &= ~sup;                                      \
                    else if (q2 == 1) kw1 &= ~sup;                                 \
                    else if (q2 == 2) kw2 &= ~sup;                                 \
                    else kw3 &= ~sup;                                              \
                }                                                                  \
            }                                                                      \
        }                                                                          \
    }
    NMS_QUAD(kw0, 0)
    NMS_QUAD(kw1, 1)
    NMS_QUAD(kw2, 2)
    NMS_QUAD(kw3, 3)
#undef NMS_QUAD

    // write per-class results (coalesced per r-group)
#pragma unroll
    for (int r = 0; r < 4; ++r) {
        const int i = (r << 6) + lane;
        if (i < TOPK) {
            const unsigned long long kq = (r == 0) ? kw0 : (r == 1) ? kw1
                                         : (r == 2) ? kw2 : kw3;
            const bool keep = (i < mk) && ((kq >> lane) & 1ULL);
            cls_scores[(size_t)t * TOPK + i] = keep ? myp[r] : NEG_INF;
            if (i < mk) cls_idx[(size_t)t * TOPK + i] = myn[r];
        }
    }
}

// ---------------------------------------------------------------- K3: per-image global top-200
__device__ __forceinline__ int blockReduceSum(int x, int* red, int tid) {
    __syncthreads();
    red[tid] = x;
    __syncthreads();
    for (int off = 128; off > 0; off >>= 1) {
        if (tid < off) red[tid] += red[tid + off];
        __syncthreads();
    }
    return red[0];
}

__global__ __launch_bounds__(256) void k3_topk(
    const float* __restrict__ cls_scores,   // [B*80*200]
    const int* __restrict__ cls_idx,        // [B*80*200]
    const float4* __restrict__ ltrb,        // [B*N]
    float* __restrict__ out)
{
    const int b = blockIdx.x;
    const int tid = threadIdx.x;
    const int NFLAT = NFG * TOPK;           // 16000
    const int PER = 63;

    __shared__ unsigned long long sel[512];
    __shared__ int scnt;
    __shared__ int red[256];

    const float* S = cls_scores + (size_t)b * NFLAT;
    float v[PER];
#pragma unroll
    for (int i = 0; i < PER; ++i) {
        int j = i * 256 + tid;
        v[i] = (j < NFLAT) ? S[j] : NEG_INF;
    }

    int lc = 0;
#pragma unroll
    for (int i = 0; i < PER; ++i) lc += (v[i] > -1e29f) ? 1 : 0;
    int validCount = blockReduceSum(lc, red, tid);

    unsigned thrBits = 0;
    if (validCount > TOPK) {
        unsigned lo = 0, hi = 0x7F800000u;
        while (lo < hi) {
            unsigned mid = (lo + hi) >> 1;
            float mf = __uint_as_float(mid);
            int c2 = 0;
#pragma unroll
            for (int i = 0; i < PER; ++i) c2 += (v[i] > mf) ? 1 : 0;
            int tot = blockReduceSum(c2, red, tid);
            if (tot < TOPK) hi = mid; else lo = mid + 1;
        }
        thrBits = lo;
    }

    __syncthreads();
    if (tid == 0) scnt = 0;
    for (int i = tid; i < 512; i += 256) sel[i] = 0ULL;
    __syncthreads();

    const bool useGE = (validCount > TOPK);
    const float thrF = __uint_as_float(thrBits);
#pragma unroll
    for (int i = 0; i < PER; ++i) {
        int j = i * 256 + tid;
        bool take = useGE ? (v[i] >= thrF) : (v[i] > -1e29f);
        if (j < NFLAT && take) {
            int pos = atomicAdd(&scnt, 1);
            if (pos < 512) {
                sel[pos] = ((unsigned long long)__float_as_uint(v[i]) << 32) |
                           (unsigned long long)(0xFFFFFFFFu - (unsigned)j);
            }
        }
    }
    __syncthreads();
    int total = min(min(scnt, 512), TOPK);

    for (unsigned k = 2; k <= 512; k <<= 1) {
        for (unsigned j = k >> 1; j > 0; j >>= 1) {
            for (unsigned i = tid; i < 512; i += 256) {
                unsigned ixj = i ^ j;
                if (ixj > i) {
                    unsigned long long a = sel[i], bb2 = sel[ixj];
                    bool desc = ((i & k) == 0);
                    if (desc ? (a < bb2) : (a > bb2)) { sel[i] = bb2; sel[ixj] = a; }
                }
            }
            __syncthreads();
        }
    }

    if (tid < TOPK) {
        size_t ob = (size_t)b * TOPK + tid;
        float4 bx = make_float4(0.f, 0.f, 0.f, 0.f);
        float lab = 0.f, sc2 = 0.f;
        if (tid < total) {
            unsigned long long key = sel[tid];
            unsigned j = 0xFFFFFFFFu - (unsigned)(key & 0xFFFFFFFFull);
            sc2 = __uint_as_float((unsigned)(key >> 32));
            unsigned cls = j / TOPK;
            int gi = cls_idx[(size_t)b * NFLAT + j];
            bx = ltrb[gi];
            lab = (float)(cls + 1);
        }
        reinterpret_cast<float4*>(out)[ob] = bx;
        out[(size_t)BATCH * TOPK * 4 + ob] = lab;
        out[(size_t)BATCH * TOPK * 4 + (size_t)BATCH * TOPK + ob] = sc2;
    }
}

// ---------------------------------------------------------------- launch
extern "C" void kernel_launch(void* const* d_in, const int* in_sizes, int n_in,
                              void* d_out, int out_size, void* d_ws, size_t ws_size,
                              hipStream_t stream) {
    (void)in_sizes; (void)n_in; (void)out_size; (void)ws_size;
    const float* bboxes = (const float*)d_in[0];   // [32,4,15130]
    const float* scores = (const float*)d_in[1];   // [32,81,15130]
    const float* dboxes = (const float*)d_in[2];   // [1,15130,4]
    float* out = (float*)d_out;

    char* ws = (char*)d_ws;
    size_t off = 0;
    float4* ltrb = (float4*)(ws + off);      off += (size_t)BATCH * NBOX * 16;    //  7,746,560
    unsigned long long* gcand = (unsigned long long*)(ws + off);
                                             off += (size_t)NTASK * GCAP * 8;     // 20,971,520
    float* cls_scores = (float*)(ws + off);  off += (size_t)NTASK * TOPK * 4;     //  2,048,000
    int*   cls_idx    = (int*)(ws + off);    off += (size_t)NTASK * TOPK * 4;     //  2,048,000
    int*   gcnt       = (int*)(ws + off);    off += (size_t)NTASK * 4;            //     10,240

    hipMemsetAsync(gcnt, 0, NTASK * sizeof(int), stream);

    k1_fused<<<BATCH * NCHUNK, 256, 0, stream>>>(bboxes, scores, dboxes, ltrb, gcand, gcnt);
    k2_nms<<<NTASK, 64, 0, stream>>>(gcand, gcnt, ltrb, cls_scores, cls_idx);
    k3_topk<<<BATCH, 256, 0, stream>>>(cls_scores, cls_idx, ltrb, out);
}